// Round 1
// baseline (20012.083 us; speedup 1.0000x reference)
//
#include <hip/hip_runtime.h>
#include <math.h>

#define EPSF 1e-5f

// ---------------- prep: weight transposes + bool-dtype detect ----------------
__global__ __launch_bounds__(256) void k_prep(
    const float* __restrict__ Whh, const float* __restrict__ Wih,
    const float* __restrict__ W2, const float* __restrict__ W3,
    const unsigned char* __restrict__ fmask,
    float* __restrict__ WT4, float* __restrict__ WxT,
    float* __restrict__ W2T, float* __restrict__ W3T, int* __restrict__ flag)
{
    int idx = blockIdx.x * 256 + threadIdx.x;
    if (idx < 196608) {                 // Whh[768][256] -> WT4[kb][768][4]
        int j = idx >> 8, k = idx & 255;
        WT4[(((k >> 2) * 768) + j) * 4 + (k & 3)] = Whh[idx];
    }
    if (idx < 105984) {                 // Wih[768][138] x-part -> WxT[128][768]
        int j = idx / 138, k = idx % 138;
        if (k < 128) WxT[k * 768 + j] = Wih[idx];
    }
    if (idx < 409600) {                 // W[co][ci][5][5] -> WT[tap][ci][co]
        int co = idx / 3200, r = idx % 3200;
        int ci = r / 25, tap = r % 25;
        int dst = (tap * 128 + ci) * 128 + co;
        W2T[dst] = W2[idx];
        W3T[dst] = W3[idx];
    }
    if (idx == 0) {                     // bool stored as int32? bytes 1,2,3 of each word all zero
        int nz = 0;
        for (int i = 0; i < 4096; i++) if ((i & 3) != 0) nz |= fmask[i];
        *flag = nz ? 0 : 1;
    }
}

// ---------------- conv1: [32,1,1024,40] -> X1[b][t][m1(8)][co(128)] ----------------
__global__ __launch_bounds__(256) void k_conv1(
    const float* __restrict__ X, const float* __restrict__ W1,
    const float* __restrict__ bb, const float* __restrict__ gg,
    const float* __restrict__ be, const float* __restrict__ mm_,
    const float* __restrict__ vv, float* __restrict__ X1)
{
    __shared__ __align__(16) float xs[8][44];
    __shared__ __align__(16) float ws[25][128];
    __shared__ float sc[128], sh[128];
    int bid = blockIdx.x;
    int b = bid >> 8, t0 = (bid & 255) << 2;
    int tid = threadIdx.x;
    for (int e = tid; e < 8 * 44; e += 256) {
        int tt = e / 44, mm = e % 44;
        int gt = t0 + tt - 2, gm = mm - 2;
        float val = 0.f;
        if (gt >= 0 && gt < 1024 && gm >= 0 && gm < 40)
            val = X[(b * 1024 + gt) * 40 + gm];
        xs[tt][mm] = val;
    }
    for (int e = tid; e < 3200; e += 256) {
        int tap = e >> 7, co = e & 127;
        ws[tap][co] = W1[co * 25 + tap];
    }
    if (tid < 128) {
        float s = gg[tid] / sqrtf(vv[tid] + EPSF);
        sc[tid] = s;
        sh[tid] = (bb[tid] - mm_[tid]) * s + be[tid];
    }
    __syncthreads();
    int cog = tid >> 5;          // 8 groups x 16 co
    int m1i = (tid >> 2) & 7;    // pooled mel
    int tp  = tid & 3;           // t'
    int co0 = cog * 16;
    float val[5][16];
#pragma unroll
    for (int p = 0; p < 5; p++)
#pragma unroll
        for (int i = 0; i < 16; i++) val[p][i] = 0.f;
#pragma unroll
    for (int dt = 0; dt < 5; dt++) {
#pragma unroll
        for (int dm = 0; dm < 5; dm++) {
            float w[16];
#pragma unroll
            for (int i = 0; i < 16; i += 4)
                *(float4*)&w[i] = *(const float4*)&ws[dt * 5 + dm][co0 + i];
#pragma unroll
            for (int p = 0; p < 5; p++) {
                float x = xs[tp + dt][m1i * 5 + p + dm];
#pragma unroll
                for (int i = 0; i < 16; i++) val[p][i] = fmaf(x, w[i], val[p][i]);
            }
        }
    }
    float outv[16];
#pragma unroll
    for (int i = 0; i < 16; i++) {
        float s = sc[co0 + i], h = sh[co0 + i];
        float mx = 0.f;
#pragma unroll
        for (int p = 0; p < 5; p++) {
            float y = fmaf(val[p][i], s, h);
            y = fmaxf(y, 0.f);
            mx = fmaxf(mx, y);
        }
        outv[i] = mx;
    }
    float* dst = &X1[(((long)(b * 1024 + t0 + tp)) * 8 + m1i) * 128 + co0];
#pragma unroll
    for (int i = 0; i < 16; i += 4) *(float4*)&dst[i] = *(float4*)&outv[i];
}

// ---------------- conv2: X1 -> X2[b][t][m2(2)][co(128)] ----------------
__global__ __launch_bounds__(256) void k_conv2(
    const float* __restrict__ X1, const float* __restrict__ W2T,
    const float* __restrict__ bb, const float* __restrict__ gg,
    const float* __restrict__ be, const float* __restrict__ mm_,
    const float* __restrict__ vv, float* __restrict__ X2)
{
    __shared__ __align__(16) float xs[20][33][12];  // [t''][ci(pad)][m']
    __shared__ __align__(16) float ws[5][32][64];   // [dm][ci][co]
    __shared__ float sc[64], sh[64];
    int bid = blockIdx.x;
    int coh = bid & 1, t0 = ((bid >> 1) & 63) << 4, b = bid >> 7;
    int co_base = coh * 64;
    int tid = threadIdx.x;
    int tp = tid & 15, cog = tid >> 4;   // 16 t' x 16 cog(4 co each)
    if (tid < 64) {
        int co = co_base + tid;
        float s = gg[co] / sqrtf(vv[co] + EPSF);
        sc[tid] = s;
        sh[tid] = (bb[co] - mm_[co]) * s + be[co];
    }
    float acc[4][8];
#pragma unroll
    for (int c = 0; c < 4; c++)
#pragma unroll
        for (int m = 0; m < 8; m++) acc[c][m] = 0.f;

    for (int cc = 0; cc < 4; cc++) {
        __syncthreads();
        for (int e = tid; e < 20 * 32 * 12; e += 256) {
            int ci = e & 31, mm = (e >> 5) % 12, tt = e / 384;
            int gt = t0 + tt - 2, gm = mm - 2;
            float v = 0.f;
            if (gt >= 0 && gt < 1024 && gm >= 0 && gm < 8)
                v = X1[(((long)(b * 1024 + gt)) * 8 + gm) * 128 + cc * 32 + ci];
            xs[tt][ci][mm] = v;
        }
        for (int dt = 0; dt < 5; dt++) {
            __syncthreads();
            for (int e = tid; e < 5 * 32 * 64; e += 256) {
                int co = e & 63, ci = (e >> 6) & 31, dm = e >> 11;
                ws[dm][ci][co] = W2T[((dt * 5 + dm) * 128 + cc * 32 + ci) * 128 + co_base + co];
            }
            __syncthreads();
            for (int ci = 0; ci < 32; ci++) {
                float x[12];
                *(float4*)&x[0] = *(const float4*)&xs[tp + dt][ci][0];
                *(float4*)&x[4] = *(const float4*)&xs[tp + dt][ci][4];
                *(float4*)&x[8] = *(const float4*)&xs[tp + dt][ci][8];
#pragma unroll
                for (int dm = 0; dm < 5; dm++) {
                    float w[4];
                    *(float4*)&w[0] = *(const float4*)&ws[dm][ci][cog * 4];
#pragma unroll
                    for (int c = 0; c < 4; c++)
#pragma unroll
                        for (int m = 0; m < 8; m++)
                            acc[c][m] = fmaf(w[c], x[m + dm], acc[c][m]);
                }
            }
        }
    }
    int t = t0 + tp;
#pragma unroll
    for (int m2 = 0; m2 < 2; m2++) {
        float4 ov;
        float* po = (float*)&ov;
#pragma unroll
        for (int c = 0; c < 4; c++) {
            float s = sc[cog * 4 + c], h = sh[cog * 4 + c];
            float mx = 0.f;
#pragma unroll
            for (int q = 0; q < 4; q++) {
                float y = fmaf(acc[c][m2 * 4 + q], s, h);
                y = fmaxf(y, 0.f);
                mx = fmaxf(mx, y);
            }
            po[c] = mx;
        }
        *(float4*)&X2[(((long)(b * 1024 + t)) * 2 + m2) * 128 + co_base + cog * 4] = ov;
    }
}

// ---------------- conv3: X2 -> F[t][b][co] (mel pooled to 1) ----------------
__global__ __launch_bounds__(256) void k_conv3(
    const float* __restrict__ X2, const float* __restrict__ W3T,
    const float* __restrict__ bb, const float* __restrict__ gg,
    const float* __restrict__ be, const float* __restrict__ mm_,
    const float* __restrict__ vv, float* __restrict__ F)
{
    __shared__ __align__(16) float xs[20][33][8];   // [t''][ci(pad)][m'] (m' 0..5 used)
    __shared__ __align__(16) float ws[5][32][64];
    __shared__ float sc[64], sh[64];
    int bid = blockIdx.x;
    int coh = bid & 1, t0 = ((bid >> 1) & 63) << 4, b = bid >> 7;
    int co_base = coh * 64;
    int tid = threadIdx.x;
    int tp = tid & 15, cog = tid >> 4;
    if (tid < 64) {
        int co = co_base + tid;
        float s = gg[co] / sqrtf(vv[co] + EPSF);
        sc[tid] = s;
        sh[tid] = (bb[co] - mm_[co]) * s + be[co];
    }
    float acc[4][2];
#pragma unroll
    for (int c = 0; c < 4; c++) { acc[c][0] = 0.f; acc[c][1] = 0.f; }

    for (int cc = 0; cc < 4; cc++) {
        __syncthreads();
        for (int e = tid; e < 20 * 32 * 8; e += 256) {
            int ci = e & 31, mm = (e >> 5) & 7, tt = e >> 8;
            int gt = t0 + tt - 2, gm = mm - 2;
            float v = 0.f;
            if (gt >= 0 && gt < 1024 && (gm == 0 || gm == 1))
                v = X2[(((long)(b * 1024 + gt)) * 2 + gm) * 128 + cc * 32 + ci];
            xs[tt][ci][mm] = v;
        }
        for (int dt = 0; dt < 5; dt++) {
            __syncthreads();
            for (int e = tid; e < 5 * 32 * 64; e += 256) {
                int co = e & 63, ci = (e >> 6) & 31, dm = e >> 11;
                ws[dm][ci][co] = W3T[((dt * 5 + dm) * 128 + cc * 32 + ci) * 128 + co_base + co];
            }
            __syncthreads();
            for (int ci = 0; ci < 32; ci++) {
                float x[8];
                *(float4*)&x[0] = *(const float4*)&xs[tp + dt][ci][0];
                *(float4*)&x[4] = *(const float4*)&xs[tp + dt][ci][4];
#pragma unroll
                for (int dm = 0; dm < 5; dm++) {
                    float w[4];
                    *(float4*)&w[0] = *(const float4*)&ws[dm][ci][cog * 4];
#pragma unroll
                    for (int c = 0; c < 4; c++) {
                        acc[c][0] = fmaf(w[c], x[0 + dm], acc[c][0]);
                        acc[c][1] = fmaf(w[c], x[1 + dm], acc[c][1]);
                    }
                }
            }
        }
    }
    float4 ov;
    float* po = (float*)&ov;
#pragma unroll
    for (int c = 0; c < 4; c++) {
        float s = sc[cog * 4 + c], h = sh[cog * 4 + c];
        float y0 = fmaxf(fmaf(acc[c][0], s, h), 0.f);
        float y1 = fmaxf(fmaf(acc[c][1], s, h), 0.f);
        po[c] = fmaxf(y0, y1);
    }
    *(float4*)&F[((long)(t0 + tp) * 32 + b) * 128 + co_base + cog * 4] = ov;
}

// ---------------- Gx = F @ Wihx.T + bih : [32768,128]x[128,768] ----------------
__global__ __launch_bounds__(256) void k_gemm(
    const float* __restrict__ F, const float* __restrict__ WxT,
    const float* __restrict__ bih, float* __restrict__ Gx)
{
    __shared__ __align__(16) float Fs[64][33];
    __shared__ __align__(16) float Ws[32][256];
    int bid = blockIdx.x;
    int jt = bid % 3, tb0 = (bid / 3) * 64;
    int tid = threadIdx.x;
    int tx = tid & 31, ty = tid >> 5;
    float acc[8][8];
#pragma unroll
    for (int i = 0; i < 8; i++)
#pragma unroll
        for (int j = 0; j < 8; j++) acc[i][j] = 0.f;
    for (int cc = 0; cc < 4; cc++) {
        __syncthreads();
        for (int e = tid; e < 64 * 32; e += 256) {
            int ci = e & 31, i = e >> 5;
            Fs[i][ci] = F[(long)(tb0 + i) * 128 + cc * 32 + ci];
        }
        for (int e = tid; e < 32 * 256; e += 256) {
            int jj = e & 255, ci = e >> 8;
            Ws[ci][jj] = WxT[(cc * 32 + ci) * 768 + jt * 256 + jj];
        }
        __syncthreads();
        for (int ci = 0; ci < 32; ci++) {
            float a[8], w[8];
#pragma unroll
            for (int i = 0; i < 8; i++) a[i] = Fs[ty * 8 + i][ci];
            *(float4*)&w[0] = *(const float4*)&Ws[ci][tx * 8];
            *(float4*)&w[4] = *(const float4*)&Ws[ci][tx * 8 + 4];
#pragma unroll
            for (int i = 0; i < 8; i++)
#pragma unroll
                for (int j = 0; j < 8; j++) acc[i][j] = fmaf(a[i], w[j], acc[i][j]);
        }
    }
    float bj[8];
#pragma unroll
    for (int j = 0; j < 8; j++) bj[j] = bih[jt * 256 + tx * 8 + j];
#pragma unroll
    for (int i = 0; i < 8; i++) {
        float o[8];
#pragma unroll
        for (int j = 0; j < 8; j++) o[j] = acc[i][j] + bj[j];
        float* dst = &Gx[(long)(tb0 + ty * 8 + i) * 768 + jt * 256 + tx * 8];
        *(float4*)&dst[0] = *(float4*)&o[0];
        *(float4*)&dst[4] = *(float4*)&o[4];
    }
}

// ---------------- sequential GRU: one workgroup per batch ----------------
__global__ __launch_bounds__(256) void k_gru(
    const float* __restrict__ WT4, const float* __restrict__ Gx,
    const float* __restrict__ Wih, const float* __restrict__ bhh_g,
    const float* __restrict__ Wf, const float* __restrict__ bf_g,
    const float* __restrict__ targets, const unsigned char* __restrict__ fmask,
    const int* __restrict__ flag, float* __restrict__ out)
{
    __shared__ __align__(16) float hlds[256];
    __shared__ float tfl[10];
    __shared__ float red[10][16];
    int b = blockIdx.x, tid = threadIdx.x;
    int j = tid;
    float wtf[3][10];
#pragma unroll
    for (int g = 0; g < 3; g++)
#pragma unroll
        for (int c = 0; c < 10; c++)
            wtf[g][c] = Wih[(j + g * 256) * 138 + 128 + c];
    float bh0 = bhh_g[j], bh1 = bhh_g[j + 256], bh2 = bhh_g[j + 512];
    int oc = tid >> 4, oseg = tid & 15;
    float wf16[16];
#pragma unroll
    for (int i = 0; i < 16; i++) wf16[i] = 0.f;
    if (tid < 160) {
#pragma unroll
        for (int i = 0; i < 16; i++) wf16[i] = Wf[oc * 256 + oseg * 16 + i];
    }
    float bfc = (tid < 10) ? bf_g[tid] : 0.f;
    int int32mode = *flag;
    hlds[j] = 0.f;
    if (tid < 10) tfl[tid] = 0.f;
    __syncthreads();
    const float4* hv = (const float4*)hlds;
    const float4* wp = ((const float4*)WT4) + j;
    for (int t = 0; t < 1024; t++) {
        float tfv[10];
#pragma unroll
        for (int c = 0; c < 10; c++) tfv[c] = tfl[c];
        const float* gx = &Gx[((long)t * 32 + b) * 768];
        float gi_r = gx[j], gi_z = gx[j + 256], gi_n = gx[j + 512];
#pragma unroll
        for (int c = 0; c < 10; c++) {
            gi_r = fmaf(tfv[c], wtf[0][c], gi_r);
            gi_z = fmaf(tfv[c], wtf[1][c], gi_z);
            gi_n = fmaf(tfv[c], wtf[2][c], gi_n);
        }
        float ar = bh0, az = bh1, an = bh2;
#pragma unroll 4
        for (int kb = 0; kb < 64; kb++) {
            float4 h4 = hv[kb];
            float4 w0 = wp[kb * 768];
            float4 w1 = wp[kb * 768 + 256];
            float4 w2 = wp[kb * 768 + 512];
            ar = fmaf(h4.x, w0.x, ar); ar = fmaf(h4.y, w0.y, ar);
            ar = fmaf(h4.z, w0.z, ar); ar = fmaf(h4.w, w0.w, ar);
            az = fmaf(h4.x, w1.x, az); az = fmaf(h4.y, w1.y, az);
            az = fmaf(h4.z, w1.z, az); az = fmaf(h4.w, w1.w, az);
            an = fmaf(h4.x, w2.x, an); an = fmaf(h4.y, w2.y, an);
            an = fmaf(h4.z, w2.z, an); an = fmaf(h4.w, w2.w, an);
        }
        float hold = hlds[j];
        float r = 1.0f / (1.0f + expf(-(gi_r + ar)));
        float z = 1.0f / (1.0f + expf(-(gi_z + az)));
        float n = tanhf(fmaf(r, an, gi_n));
        float hnew = (1.0f - z) * n + z * hold;
        __syncthreads();
        hlds[j] = hnew;
        __syncthreads();
        if (tid < 160) {
            float p = 0.f;
            const float* hh = &hlds[oseg * 16];
#pragma unroll
            for (int i = 0; i < 16; i++) p = fmaf(hh[i], wf16[i], p);
            red[oc][oseg] = p;
        }
        __syncthreads();
        if (tid < 10) {
            float o = bfc;
#pragma unroll
            for (int s = 0; s < 16; s++) o += red[tid][s];
            out[((long)b * 1024 + t) * 10 + tid] = o;
            float pred = (o > 0.f) ? 1.f : 0.f;
            int fmv = int32mode ? ((const int*)fmask)[t * 32 + b]
                                : (int)fmask[t * 32 + b];
            tfl[tid] = fmv ? targets[((long)b * 1024 + t) * 10 + tid] : pred;
        }
        __syncthreads();
    }
}

extern "C" void kernel_launch(void* const* d_in, const int* in_sizes, int n_in,
                              void* d_out, int out_size, void* d_ws, size_t ws_size,
                              hipStream_t stream) {
    (void)in_sizes; (void)n_in; (void)out_size; (void)ws_size;
    const float* features = (const float*)d_in[0];
    const float* targets  = (const float*)d_in[1];
    const unsigned char* fmask = (const unsigned char*)d_in[2];
    const float* W1  = (const float*)d_in[3];
    const float* b1  = (const float*)d_in[4];
    const float* g1  = (const float*)d_in[5];
    const float* be1 = (const float*)d_in[6];
    const float* m1  = (const float*)d_in[7];
    const float* v1  = (const float*)d_in[8];
    const float* W2  = (const float*)d_in[9];
    const float* b2  = (const float*)d_in[10];
    const float* g2  = (const float*)d_in[11];
    const float* be2 = (const float*)d_in[12];
    const float* m2  = (const float*)d_in[13];
    const float* v2  = (const float*)d_in[14];
    const float* W3  = (const float*)d_in[15];
    const float* b3  = (const float*)d_in[16];
    const float* g3  = (const float*)d_in[17];
    const float* be3 = (const float*)d_in[18];
    const float* m3  = (const float*)d_in[19];
    const float* v3  = (const float*)d_in[20];
    const float* Wih = (const float*)d_in[21];
    const float* Whh = (const float*)d_in[22];
    const float* bih = (const float*)d_in[23];
    const float* bhh = (const float*)d_in[24];
    const float* Wf  = (const float*)d_in[25];
    const float* bf  = (const float*)d_in[26];

    char* w = (char*)d_ws;
    float* WT4 = (float*)(w + 0);                       // 786432 B
    float* WxT = (float*)(w + 786432);                  // 393216 B
    float* W2T = (float*)(w + 1179648);                 // 1638400 B
    float* W3T = (float*)(w + 2818048);                 // 1638400 B
    int*   flag = (int*)(w + 4456448);                  // 512 B slot
    float* X1  = (float*)(w + 4456960);                 // 128 MB; reused as Gx after conv2
    float* Gx  = X1;
    float* X2  = (float*)(w + 4456960 + 134217728);     // 32 MB
    float* F   = (float*)(w + 4456960 + 134217728 + 33554432); // 16 MB
    float* out = (float*)d_out;

    k_prep<<<1600, 256, 0, stream>>>(Whh, Wih, W2, W3, fmask, WT4, WxT, W2T, W3T, flag);
    k_conv1<<<8192, 256, 0, stream>>>(features, W1, b1, g1, be1, m1, v1, X1);
    k_conv2<<<4096, 256, 0, stream>>>(X1, W2T, b2, g2, be2, m2, v2, X2);
    k_conv3<<<4096, 256, 0, stream>>>(X2, W3T, b3, g3, be3, m3, v3, F);
    k_gemm<<<1536, 256, 0, stream>>>(F, WxT, bih, Gx);
    k_gru<<<32, 256, 0, stream>>>(WT4, Gx, Wih, bhh, Wf, bf, targets, fmask, flag, out);
}